// Round 1
// 333.517 us; speedup vs baseline: 1.0149x; 1.0149x over previous
//
#include <hip/hip_runtime.h>

// ============================================================================
// ExtraMHSA pipeline for MI355X (gfx950).  R6: fused flash-style attention.
//
//   prep_all   : pos embeds, BN-fold weights->bf16, zero O/l
//   front_k    : x ->(regs) x1=silu(conv1) ->(LDS) q,k,v,p -> LT/RT/Vv/pT
//   fused_attn : per (i-tile 128 x j-part 640):  S = L.R^T (LDS-staged R),
//                P = exp(S) (no-max softmax, scores bounded ~26),
//                l[i] += rowsum (reg-accumulated, one atomic/block),
//                O[i][c] += P.V^T  with P transposed through per-wave LDS
//                (never materialized to HBM) and V read direct from global
//                (32KB j-tile, L1-resident).  Both heads in one 1000-block
//                dispatch: bid<500 -> head1 (KD=256), else head2 (KD=128).
//   final_k    : out = x + silu(bn(conv2(O1/l1))) + silu(bn(conv3(O2/l2)))
//
// R6 rationale: score_k+pv_k round-tripped 82 MB of P through HBM per head
// at 13% MfmaUtil / 23% HBM — latency-bound on the store/reload pipeline.
// Fusion removes 328 MB of HBM traffic and 2 launches.
// LDS handoff discipline (R5 lesson): cross-wave Rs staging uses
// __syncthreads(); per-wave T-buffer transpose uses sched_barrier(0) +
// s_waitcnt lgkmcnt(0) fences (compiler may otherwise hoist ds_read above
// ds_write across lanes).
// ============================================================================

typedef unsigned short u16;
typedef __attribute__((ext_vector_type(8))) short bf16x8;   // 8 bf16 = 4 VGPRs
typedef __attribute__((ext_vector_type(4))) float f32x4;    // MFMA C/D frag
typedef __attribute__((ext_vector_type(4))) unsigned int u32x4;

#define HW 6400
#define BN_EPS 1e-5f

__device__ __forceinline__ u16 f2b(float f) {       // fp32 -> bf16 RNE
  unsigned u = __float_as_uint(f);
  u += 0x7fffu + ((u >> 16) & 1u);
  return (u16)(u >> 16);
}
__device__ __forceinline__ unsigned pack2(float a, float b) {
  return (unsigned)f2b(a) | ((unsigned)f2b(b) << 16);
}
__device__ __forceinline__ f32x4 MFMA(bf16x8 a, bf16x8 b, f32x4 c) {
  return __builtin_amdgcn_mfma_f32_16x16x32_bf16(a, b, c, 0, 0, 0);
}
__device__ __forceinline__ float silu_f(float y) {
  return y / (1.0f + __expf(-y));
}
__device__ __forceinline__ bf16x8 pack8(f32x4 lo, f32x4 hi, float sc) {
  union { bf16x8 v; uint4 u; } r;
  r.u.x = pack2(lo[0] * sc, lo[1] * sc);
  r.u.y = pack2(lo[2] * sc, lo[3] * sc);
  r.u.z = pack2(hi[0] * sc, hi[1] * sc);
  r.u.w = pack2(hi[2] * sc, hi[3] * sc);
  return r.v;
}
// Wave-local LDS write->read handoff: compiler fence + hw drain.
__device__ __forceinline__ void lds_fence() {
  __builtin_amdgcn_sched_barrier(0);
  asm volatile("s_waitcnt lgkmcnt(0)" ::: "memory");
  __builtin_amdgcn_sched_barrier(0);
}

// ---------------------------------------------------------------------------
// prep_all: [0,80) pos embeds; [80,144) weight BN-fold; [144,176) zero O/l.
// ---------------------------------------------------------------------------
__global__ void prep_all(
    const float* __restrict__ rel_h, const float* __restrict__ rel_w,
    const float* __restrict__ ef_h, const float* __restrict__ ef_w,
    const float* __restrict__ w1, const float* __restrict__ g1, const float* __restrict__ b1,
    const float* __restrict__ m1, const float* __restrict__ v1,
    const float* __restrict__ w2, const float* __restrict__ g2, const float* __restrict__ b2,
    const float* __restrict__ m2, const float* __restrict__ v2,
    const float* __restrict__ w3, const float* __restrict__ g3, const float* __restrict__ b3,
    const float* __restrict__ m3, const float* __restrict__ v3,
    const float* __restrict__ wq, const float* __restrict__ bq,
    const float* __restrict__ wk, const float* __restrict__ bk,
    const float* __restrict__ wv, const float* __restrict__ bv,
    const float* __restrict__ wp, const float* __restrict__ bp,
    u16* __restrict__ LT, u16* __restrict__ efT, u16* __restrict__ efc,
    u16* __restrict__ w1b, float* __restrict__ b1e,
    u16* __restrict__ Wcat, float* __restrict__ bcat,
    u16* __restrict__ w2b, float* __restrict__ b2e,
    u16* __restrict__ w3b, float* __restrict__ b3e,
    float* __restrict__ Obuf, float* __restrict__ lbuf)
{
  const int b = blockIdx.x;
  const int t = threadIdx.x;
  if (b < 80) {
    const int h = b;
    const int c0 = (t & 63) * 2;
    const float rh0 = rel_h[c0 * 80 + h], rh1 = rel_h[(c0 + 1) * 80 + h];
    const float eh0 = ef_h[c0 * 80 + h], eh1 = ef_h[(c0 + 1) * 80 + h];
    for (int wcol = (t >> 6); wcol < 80; wcol += 4) {
      const int i = h * 80 + wcol;
      float rw0 = rel_w[c0 * 80 + wcol], rw1 = rel_w[(c0 + 1) * 80 + wcol];
      float ew0 = ef_w[c0 * 80 + wcol], ew1 = ef_w[(c0 + 1) * 80 + wcol];
      *(unsigned*)&LT[(size_t)i * 256 + 128 + c0] = pack2(rh0 + rw0, rh1 + rw1);
      float e0 = eh0 + ew0, e1 = eh1 + ew1;
      *(unsigned*)&efT[(size_t)i * 128 + c0] = pack2(e0, e1);
      efc[(size_t)c0 * HW + i] = f2b(e0);
      efc[(size_t)(c0 + 1) * HW + i] = f2b(e1);
    }
  } else if (b < 144) {
    const int tid = (b - 80) * 256 + t;
    const int stride = 64 * 256;
    for (int idx = tid; idx < 128 * 256; idx += stride) {
      int o = idx >> 8;
      float s = g1[o] * rsqrtf(v1[o] + BN_EPS);
      w1b[idx] = f2b(w1[idx] * s);
    }
    for (int idx = tid; idx < 128; idx += stride) {
      float s = g1[idx] * rsqrtf(v1[idx] + BN_EPS);
      b1e[idx] = b1[idx] - m1[idx] * s;
    }
    for (int idx = tid; idx < 4 * 128 * 128; idx += stride) {
      int which = idx >> 14, r = idx & 16383;
      const float* src = which == 0 ? wq : which == 1 ? wk : which == 2 ? wv : wp;
      Wcat[idx] = f2b(src[r]);
    }
    for (int idx = tid; idx < 512; idx += stride) {
      int which = idx >> 7, r = idx & 127;
      const float* src = which == 0 ? bq : which == 1 ? bk : which == 2 ? bv : bp;
      bcat[idx] = src[r];
    }
    for (int idx = tid; idx < 256 * 128; idx += stride) {
      int o = idx >> 7;
      float s2 = g2[o] * rsqrtf(v2[o] + BN_EPS);
      w2b[idx] = f2b(w2[idx] * s2);
      float s3 = g3[o] * rsqrtf(v3[o] + BN_EPS);
      w3b[idx] = f2b(w3[idx] * s3);
    }
    for (int idx = tid; idx < 256; idx += stride) {
      float s2 = g2[idx] * rsqrtf(v2[idx] + BN_EPS);
      b2e[idx] = b2[idx] - m2[idx] * s2;
      float s3 = g3[idx] * rsqrtf(v3[idx] + BN_EPS);
      b3e[idx] = b3[idx] - m3[idx] * s3;
    }
  } else {
    const int tid = (b - 144) * 256 + t;
    const int stride = 32 * 256;
    f32x4 z = {0.f, 0.f, 0.f, 0.f};
    for (int idx = tid; idx < 2 * HW * 128 / 4; idx += stride)
      ((f32x4*)Obuf)[idx] = z;
    for (int idx = tid; idx < 2 * HW / 4; idx += stride)
      ((f32x4*)lbuf)[idx] = z;
  }
}

// ---------------------------------------------------------------------------
// front_k: fused  x -> x1=silu(bn(conv1(x))) -> {q,k,v,p} -> LT/RT/Vv/pT.
// grid <<<200, 128>>>: 2 waves x 16 i-rows. Barriers guard every LDS
// write->read handoff (uniform across the block).
// ---------------------------------------------------------------------------
__global__ __launch_bounds__(128) void front_k(
    const float* __restrict__ x,
    const u16* __restrict__ w1b, const float* __restrict__ b1e,
    const u16* __restrict__ Wcat, const float* __restrict__ bcat,
    u16* __restrict__ LT, u16* __restrict__ RT, u16* __restrict__ Vv,
    u16* __restrict__ pT)
{
  __shared__ __align__(16) u16 tr[2][16][136];
  const int t = threadIdx.x, w = t >> 6, lane = t & 63, jl = lane & 15, q = lane >> 4;
  const int i0 = blockIdx.x * 32 + w * 16;

  // ---- x A-fragments (k = channel d), built from strided fp32 loads
  bf16x8 afr[8];
#pragma unroll
  for (int ks = 0; ks < 8; ++ks) {
    union { bf16x8 v; u16 e[8]; } fa;
#pragma unroll
    for (int e = 0; e < 8; ++e)
      fa.e[e] = f2b(x[(size_t)(ks * 32 + q * 8 + e) * HW + i0 + jl]);
    afr[ks] = fa.v;
  }
  // ---- x1 = silu(x . w1b + b1e)
  f32x4 acc[8];
#pragma unroll
  for (int nf = 0; nf < 8; ++nf) acc[nf] = (f32x4){0.f, 0.f, 0.f, 0.f};
#pragma unroll
  for (int ks = 0; ks < 8; ++ks)
#pragma unroll
    for (int nf = 0; nf < 8; ++nf) {
      bf16x8 b = *(const bf16x8*)(w1b + (size_t)(nf * 16 + jl) * 256 + ks * 32 + q * 8);
      acc[nf] = MFMA(afr[ks], b, acc[nf]);
    }
#pragma unroll
  for (int nf = 0; nf < 8; ++nf) {
    const int c = nf * 16 + jl;
    const float bias = b1e[c];
#pragma unroll
    for (int r = 0; r < 4; ++r)
      tr[w][q * 4 + r][c] = f2b(silu_f(acc[nf][r] + bias));
  }
  __syncthreads();                               // x1 writes -> xa reads
  bf16x8 xa[4];
#pragma unroll
  for (int ks = 0; ks < 4; ++ks)
    xa[ks] = *(const bf16x8*)&tr[w][jl][ks * 32 + q * 8];

  // ---- q,k,v,p projections
#pragma unroll
  for (int nc = 0; nc < 4; ++nc) {
    f32x4 a2[8];
#pragma unroll
    for (int nf = 0; nf < 8; ++nf) a2[nf] = (f32x4){0.f, 0.f, 0.f, 0.f};
#pragma unroll
    for (int ks = 0; ks < 4; ++ks)
#pragma unroll
      for (int nf = 0; nf < 8; ++nf) {
        bf16x8 b = *(const bf16x8*)(Wcat + (size_t)(nc * 128 + nf * 16 + jl) * 128 + ks * 32 + q * 8);
        a2[nf] = MFMA(xa[ks], b, a2[nf]);
      }
    if (nc == 2) {                               // V: [c][i] direct store
#pragma unroll
      for (int nf = 0; nf < 8; ++nf) {
        const int c = nf * 16 + jl;
        const float bias = bcat[256 + c];
        uint2 pk;
        pk.x = pack2(a2[nf][0] + bias, a2[nf][1] + bias);
        pk.y = pack2(a2[nf][2] + bias, a2[nf][3] + bias);
        *(uint2*)(Vv + (size_t)c * HW + i0 + q * 4) = pk;
      }
    } else {
      __syncthreads();                           // prev reads done -> overwrite
#pragma unroll
      for (int nf = 0; nf < 8; ++nf) {
        const int c = nf * 16 + jl;
        const float bias = bcat[nc * 128 + c];
#pragma unroll
        for (int r = 0; r < 4; ++r)
          tr[w][q * 4 + r][c] = f2b(a2[nf][r] + bias);
      }
      __syncthreads();                           // writes -> row reads
#pragma unroll
      for (int r = 0; r < 16; ++r) {
        unsigned val = *(const unsigned*)&tr[w][r][lane * 2];
        const size_t row = (size_t)(i0 + r);
        if (nc == 0) {
          *(unsigned*)(LT + row * 256 + lane * 2) = val;
          *(unsigned*)(RT + row * 256 + 128 + lane * 2) = val;
        } else if (nc == 1) {
          *(unsigned*)(RT + row * 256 + lane * 2) = val;
        } else {
          *(unsigned*)(pT + row * 128 + lane * 2) = val;
        }
      }
    }
  }
}

// ---------------------------------------------------------------------------
// fused_attn body: one i-tile (128 rows, 4 waves x 32i) x one j-part (640 j,
// 5 steps of 128).  Per step:
//   stage R[128][128] per K-half in LDS (XOR-8 chunk swizzle) -> S MFMAs,
//   exp in-register (+ rowsum accum), transpose P 16x128 per (wave,mt) into
//   per-wave LDS T-buffers, PV MFMAs with V B-frags direct from global.
// Epilogue: one atomicAdd set for l and O.
// ---------------------------------------------------------------------------
template <int KD>
__device__ __forceinline__ void attn_body(
    const u16* __restrict__ Lt,     // [HW][KD]
    const u16* __restrict__ Rt,     // [HW][KD]
    const u16* __restrict__ Vm,     // [128][HW]
    float* __restrict__ O,          // [HW][128]
    float* __restrict__ lv,         // [HW]
    int bid, u16* __restrict__ Rs, u16* __restrict__ T0, u16* __restrict__ T1)
{
  const int t = threadIdx.x, lane = t & 63, w = t >> 6, jl = lane & 15, q = lane >> 4;
  const int it = bid / 10, jp = bid % 10;
  const int i0w = it * 128 + w * 32;
  constexpr int NKS = KD / 32;

  // A fragments (L rows for this wave) resident in registers
  bf16x8 afr[2][NKS];
#pragma unroll
  for (int mt = 0; mt < 2; ++mt)
#pragma unroll
    for (int ks = 0; ks < NKS; ++ks)
      afr[mt][ks] = *(const bf16x8*)(Lt + (size_t)(i0w + mt * 16 + jl) * KD + ks * 32 + q * 8);

  f32x4 o[2][8];
#pragma unroll
  for (int mt = 0; mt < 2; ++mt)
#pragma unroll
    for (int cf = 0; cf < 8; ++cf) o[mt][cf] = (f32x4){0.f, 0.f, 0.f, 0.f};
  float lacc[2][4] = {{0.f, 0.f, 0.f, 0.f}, {0.f, 0.f, 0.f, 0.f}};

  for (int stp = 0; stp < 5; ++stp) {
    const int jj = jp * 640 + stp * 128;

    f32x4 s[2][8];
#pragma unroll
    for (int mt = 0; mt < 2; ++mt)
#pragma unroll
      for (int nf = 0; nf < 8; ++nf) s[mt][nf] = (f32x4){0.f, 0.f, 0.f, 0.f};

    // ---- score: S = L . R^T over K halves of 128
#pragma unroll
    for (int h = 0; h < KD / 128; ++h) {
      __syncthreads();                           // prev Rs reads done
#pragma unroll
      for (int cc = 0; cc < 8; ++cc) {
        const int jr = w * 32 + cc * 4 + (lane >> 4);
        const int cp = lane & 15;
        const int ch = (cp & ~7) | ((cp ^ jr) & 7);
        *(u32x4*)(Rs + jr * 128 + cp * 8) =
            *(const u32x4*)(Rt + (size_t)(jj + jr) * KD + h * 128 + ch * 8);
      }
      __syncthreads();                           // stage done
#pragma unroll
      for (int nf = 0; nf < 8; ++nf) {
        const int row = nf * 16 + jl;
#pragma unroll
        for (int l = 0; l < 4; ++l) {
          const int ch = (l * 4 + q) ^ (jl & 7); // un-swizzle
          bf16x8 b = *(const bf16x8*)(Rs + row * 128 + ch * 8);
          s[0][nf] = MFMA(afr[0][h * 4 + l], b, s[0][nf]);
          s[1][nf] = MFMA(afr[1][h * 4 + l], b, s[1][nf]);
        }
      }
    }

    // ---- P = exp(S); accumulate rowsums in registers
#pragma unroll
    for (int mt = 0; mt < 2; ++mt)
#pragma unroll
      for (int nf = 0; nf < 8; ++nf)
#pragma unroll
        for (int r = 0; r < 4; ++r) {
          float p = __expf(s[mt][nf][r]);
          s[mt][nf][r] = p;
          lacc[mt][r] += p;
        }

    // ---- transpose P C-frags -> per-wave LDS (A-frag layout)
    lds_fence();                                 // prev pa reads done
#pragma unroll
    for (int nf = 0; nf < 8; ++nf)
#pragma unroll
      for (int r = 0; r < 4; ++r) {
        T0[(q * 4 + r) * 136 + nf * 16 + jl] = f2b(s[0][nf][r]);
        T1[(q * 4 + r) * 136 + nf * 16 + jl] = f2b(s[1][nf][r]);
      }
    lds_fence();                                 // writes -> reads

    // ---- PV: O += P . V^T, V B-frags direct from global (L1-resident tile)
#pragma unroll
    for (int ks2 = 0; ks2 < 4; ++ks2) {
      bf16x8 pa0 = *(const bf16x8*)(T0 + jl * 136 + ks2 * 32 + q * 8);
      bf16x8 pa1 = *(const bf16x8*)(T1 + jl * 136 + ks2 * 32 + q * 8);
#pragma unroll
      for (int cf = 0; cf < 8; ++cf) {
        bf16x8 bv = *(const bf16x8*)(Vm + (size_t)(cf * 16 + jl) * HW + jj + ks2 * 32 + q * 8);
        o[0][cf] = MFMA(pa0, bv, o[0][cf]);
        o[1][cf] = MFMA(pa1, bv, o[1][cf]);
      }
    }
  }

  // ---- epilogue: l rowsum reduce + atomics, O atomics (L2-resident)
#pragma unroll
  for (int mt = 0; mt < 2; ++mt) {
    float rs[4] = {lacc[mt][0], lacc[mt][1], lacc[mt][2], lacc[mt][3]};
#pragma unroll
    for (int d = 1; d < 16; d <<= 1)
#pragma unroll
      for (int r = 0; r < 4; ++r) rs[r] += __shfl_xor(rs[r], d);
    if (jl == 0) {
#pragma unroll
      for (int r = 0; r < 4; ++r)
        atomicAdd(&lv[i0w + mt * 16 + q * 4 + r], rs[r]);
    }
  }
#pragma unroll
  for (int mt = 0; mt < 2; ++mt) {
    const int ib = i0w + mt * 16 + q * 4;
#pragma unroll
    for (int cf = 0; cf < 8; ++cf) {
      const int c = cf * 16 + jl;
#pragma unroll
      for (int r = 0; r < 4; ++r)
        atomicAdd(&O[(size_t)(ib + r) * 128 + c], o[mt][cf][r]);
    }
  }
}

// grid <<<1000, 256>>>: bid<500 head1 (KD=256), else head2 (KD=128).
// LDS: Rs 32KB + 4 waves x 2 T-buffers x 16x136 u16 = 66 KB -> 2 blocks/CU.
__global__ __launch_bounds__(256, 2) void fused_attn(
    const u16* __restrict__ LT, const u16* __restrict__ RT, const u16* __restrict__ Vv,
    const u16* __restrict__ pT, const u16* __restrict__ efT, const u16* __restrict__ efc,
    float* __restrict__ Obuf, float* __restrict__ lbuf)
{
  __shared__ __align__(16) u16 Rs[128 * 128];
  __shared__ __align__(16) u16 Tb[4][2][16 * 136];
  const int w = threadIdx.x >> 6;
  const int bid = blockIdx.x;
  if (bid < 500)
    attn_body<256>(LT, RT, Vv, Obuf, lbuf, bid, Rs, Tb[w][0], Tb[w][1]);
  else
    attn_body<128>(pT, efT, efc, Obuf + (size_t)HW * 128, lbuf + HW, bid - 500,
                   Rs, Tb[w][0], Tb[w][1]);
}

// ---------------------------------------------------------------------------
// final_k: out[d][i] = x[d][i] + silu(o1.w2b + b2e) + silu(o2.w3b + b3e),
// o?[i][c] = O[h][i][c] / l[h][i], built as bf16 A-frags on the fly.
// grid dim3(100, 2), 256 thr.
// ---------------------------------------------------------------------------
__global__ __launch_bounds__(256) void final_k(
    const float* __restrict__ Obuf,    // [2][HW][128]
    const float* __restrict__ lbuf,    // [2][HW]
    const u16* __restrict__ w2b, const float* __restrict__ b2e,
    const u16* __restrict__ w3b, const float* __restrict__ b3e,
    const float* __restrict__ x, float* __restrict__ outp)
{
  const int t = threadIdx.x, w = t >> 6, lane = t & 63, jl = lane & 15, q = lane >> 4;
  const int i0 = blockIdx.x * 64 + w * 16;
  const int nc = blockIdx.y;
  const int row = i0 + jl;

  const float inv1 = 1.0f / lbuf[row];
  const float inv2 = 1.0f / lbuf[HW + row];
  const float* O1 = Obuf + (size_t)row * 128;
  const float* O2 = Obuf + (size_t)(HW + row) * 128;

  f32x4 a1[8], a2[8];
#pragma unroll
  for (int nf = 0; nf < 8; ++nf) {
    a1[nf] = (f32x4){0.f, 0.f, 0.f, 0.f};
    a2[nf] = (f32x4){0.f, 0.f, 0.f, 0.f};
  }
#pragma unroll
  for (int ks = 0; ks < 4; ++ks) {
    f32x4 s1a = *(const f32x4*)(O1 + ks * 32 + q * 8);
    f32x4 s1b = *(const f32x4*)(O1 + ks * 32 + q * 8 + 4);
    f32x4 s2a = *(const f32x4*)(O2 + ks * 32 + q * 8);
    f32x4 s2b = *(const f32x4*)(O2 + ks * 32 + q * 8 + 4);
    bf16x8 fa1 = pack8(s1a, s1b, inv1);
    bf16x8 fa2 = pack8(s2a, s2b, inv2);
#pragma unroll
    for (int nf = 0; nf < 8; ++nf) {
      bf16x8 b2f = *(const bf16x8*)(w2b + (size_t)(nc * 128 + nf * 16 + jl) * 128 + ks * 32 + q * 8);
      bf16x8 b3f = *(const bf16x8*)(w3b + (size_t)(nc * 128 + nf * 16 + jl) * 128 + ks * 32 + q * 8);
      a1[nf] = MFMA(fa1, b2f, a1[nf]);
      a2[nf] = MFMA(fa2, b3f, a2[nf]);
    }
  }
#pragma unroll
  for (int nf = 0; nf < 8; ++nf) {
    const int d = nc * 128 + nf * 16 + jl;
    const float bb2 = b2e[d], bb3 = b3e[d];
    const size_t base = (size_t)d * HW + i0 + q * 4;
    f32x4 xv = *(const f32x4*)(x + base);
    f32x4 rv;
#pragma unroll
    for (int r = 0; r < 4; ++r)
      rv[r] = xv[r] + silu_f(a1[nf][r] + bb2) + silu_f(a2[nf][r] + bb3);
    *(f32x4*)(outp + base) = rv;
  }
}

// ---------------------------------------------------------------------------
extern "C" void kernel_launch(void* const* d_in, const int* in_sizes, int n_in,
                              void* d_out, int out_size, void* d_ws, size_t ws_size,
                              hipStream_t stream)
{
  (void)in_sizes; (void)n_in; (void)out_size; (void)ws_size;
  const float* x   = (const float*)d_in[0];
  const float* w1  = (const float*)d_in[1];
  const float* g1  = (const float*)d_in[2];
  const float* b1  = (const float*)d_in[3];
  const float* m1  = (const float*)d_in[4];
  const float* v1  = (const float*)d_in[5];
  const float* w2  = (const float*)d_in[6];
  const float* g2  = (const float*)d_in[7];
  const float* b2  = (const float*)d_in[8];
  const float* m2  = (const float*)d_in[9];
  const float* v2  = (const float*)d_in[10];
  const float* w3  = (const float*)d_in[11];
  const float* g3  = (const float*)d_in[12];
  const float* b3  = (const float*)d_in[13];
  const float* m3  = (const float*)d_in[14];
  const float* v3  = (const float*)d_in[15];
  const float* wq  = (const float*)d_in[16];
  const float* bq  = (const float*)d_in[17];
  const float* wk  = (const float*)d_in[18];
  const float* bk  = (const float*)d_in[19];
  const float* wv  = (const float*)d_in[20];
  const float* bv  = (const float*)d_in[21];
  const float* wp  = (const float*)d_in[22];
  const float* bp  = (const float*)d_in[23];
  const float* rel_h = (const float*)d_in[24];
  const float* rel_w = (const float*)d_in[25];
  const float* ef_h  = (const float*)d_in[26];
  const float* ef_w  = (const float*)d_in[27];
  float* outp = (float*)d_out;

  char* ws = (char*)d_ws;
  size_t off = 0;
  auto alloc = [&](size_t bytes) -> void* {
    void* p = ws + off;
    off += (bytes + 511) & ~(size_t)511;
    return p;
  };
  u16* LT    = (u16*)alloc((size_t)HW * 256 * 2);
  u16* RT    = (u16*)alloc((size_t)HW * 256 * 2);
  u16* pT    = (u16*)alloc((size_t)HW * 128 * 2);
  u16* efT   = (u16*)alloc((size_t)HW * 128 * 2);
  u16* efc   = (u16*)alloc((size_t)HW * 128 * 2);
  u16* Vv    = (u16*)alloc((size_t)HW * 128 * 2);
  float* Obuf = (float*)alloc((size_t)2 * HW * 128 * 4);    // 6.55 MB
  float* lbuf = (float*)alloc((size_t)2 * HW * 4);
  u16* w1b   = (u16*)alloc(128 * 256 * 2);
  float* b1e = (float*)alloc(128 * 4);
  u16* Wcat  = (u16*)alloc(512 * 128 * 2);
  float* bcat = (float*)alloc(512 * 4);
  u16* w2b   = (u16*)alloc(256 * 128 * 2);
  float* b2e = (float*)alloc(256 * 4);
  u16* w3b   = (u16*)alloc(256 * 128 * 2);
  float* b3e = (float*)alloc(256 * 4);

  prep_all<<<176, 256, 0, stream>>>(rel_h, rel_w, ef_h, ef_w,
                                    w1, g1, b1, m1, v1, w2, g2, b2, m2, v2,
                                    w3, g3, b3, m3, v3, wq, bq, wk, bk, wv, bv, wp, bp,
                                    LT, efT, efc,
                                    w1b, b1e, Wcat, bcat, w2b, b2e, w3b, b3e,
                                    Obuf, lbuf);
  front_k<<<200, 128, 0, stream>>>(x, w1b, b1e, Wcat, bcat, LT, RT, Vv, pT);
  fused_attn<<<1000, 256, 0, stream>>>(LT, RT, Vv, pT, efT, efc, Obuf, lbuf);
  final_k<<<dim3(100, 2), 256, 0, stream>>>(Obuf, lbuf, w2b, b2e, w3b, b3e, x, outp);
}